// Round 2
// baseline (322.077 us; speedup 1.0000x reference)
//
#include <hip/hip_runtime.h>
#include <math.h>

#define BB 512
#define TT 1024
#define NS 50

typedef _Float16 half2_t __attribute__((ext_vector_type(2)));

static __device__ __forceinline__ half2_t pk_h2(float a, float b) {
    auto r = __builtin_amdgcn_cvt_pkrtz(a, b);   // packs (a -> lo, b -> hi)
    return __builtin_bit_cast(half2_t, r);
}
static __device__ __forceinline__ float wave_sum_f(float v) {
    #pragma unroll
    for (int k = 32; k >= 1; k >>= 1) v += __shfl_xor(v, k, 64);
    return v;
}
static __device__ __forceinline__ int wave_sum_i(int v) {
    #pragma unroll
    for (int k = 32; k >= 1; k >>= 1) v += __shfl_xor(v, k, 64);
    return v;
}
#define FDOT(a, b, c) __builtin_amdgcn_fdot2((a), (b), (c), false)

__global__ __launch_bounds__(128, 1) void crf_nll_kernel(
    const float* __restrict__ feat,    // (B, T, N)
    const float* __restrict__ trans,   // (N, N)
    const int*   __restrict__ tags,    // (B, T)
    const int*   __restrict__ mask,    // (B, T)
    float* __restrict__ out)           // (B,)
{
    const int b    = blockIdx.x;
    const int tid  = threadIdx.x;
    const int w    = tid >> 6;        // wave 0 = forward, wave 1 = backward (zeta)
    const int lane = tid & 63;
    const int jj   = (lane < NS) ? lane : 0;

    __shared__ float sh_comb[64];
    __shared__ float sh_sc[2];
    __shared__ int   sh_Kb;

    // --- E fragments as 25 named packed-f16 regs (register-resident).
    // fwd: e_m = (E[2m][j], E[2m+1][j]);  bwd: e_m = (E[j][2m], E[j][2m+1])
    // exp(-10000) == 0 exactly -> forbidden transitions vanish.
#define INIT_E(m) half2_t e##m; { \
        int r0 = w ? (jj * NS + 2*(m)) : ((2*(m)) * NS + jj); \
        int r1 = r0 + (w ? 1 : NS); \
        float x0 = __expf(trans[r0]); \
        float x1 = __expf(trans[r1]); \
        if (lane >= NS) { x0 = 0.f; x1 = 0.f; } \
        e##m = pk_h2(x0, x1); }
    INIT_E(0)  INIT_E(1)  INIT_E(2)  INIT_E(3)  INIT_E(4)
    INIT_E(5)  INIT_E(6)  INIT_E(7)  INIT_E(8)  INIT_E(9)
    INIT_E(10) INIT_E(11) INIT_E(12) INIT_E(13) INIT_E(14)
    INIT_E(15) INIT_E(16) INIT_E(17) INIT_E(18) INIT_E(19)
    INIT_E(20) INIT_E(21) INIT_E(22) INIT_E(23) INIT_E(24)
#undef INIT_E

    // --- sequence length (mask is a prefix of ones); uniform ---
    int cnt = 0;
    for (int t = lane; t < TT; t += 64) cnt += mask[b * TT + t];
    const int len = wave_sum_i(cnt);
    const int tm  = (len - 1) >> 1;          // cut point
    const int nst = w ? (len - 1 - tm) : tm; // steps this wave runs

    const float* fb = feat + (size_t)b * TT * NS;

    // --- prob-domain init: fwd u=exp(alpha0); bwd u=exp(zeta_{len-1}), zeta=beta+feat
    float u;
    if (w == 0) u = (lane < NS) ? __expf(trans[jj] + fb[jj]) : 0.f;
    else        u = (lane < NS) ? __expf(trans[jj * NS + 1] + fb[(size_t)(len - 1) * NS + jj]) : 0.f;
    int K = 0, kp, rr;
    { int bb2 = __builtin_amdgcn_readlane(__float_as_int(u), 7);
      kp = ((bb2 >> 23) & 255) - 127; rr = (127 - kp) << 23; }

    // --- one step. eexp = exp(feat row value), staged one step ahead off-chain. ---
    // Broadcast of the 25 packed state-pairs via v_readlane -> SGPR (no LDS).
    auto step = [&](float eexp) {
        K += kp;
        float p = u * __int_as_float(rr);             // lane7 in [1,2); others e^±spread
        int pn_ = __builtin_amdgcn_update_dpp(
            __float_as_int(p), __float_as_int(p), 0xB1, 0xF, 0xF, true); // lane^1
        float pnf = __int_as_float(pn_);
        half2_t pk = pk_h2(p, pnf);                   // even lane: (u[2m], u[2m+1])
        int pki = __builtin_bit_cast(int, pk);
        float s0 = 0.f, s1 = 0.f, s2 = 0.f, s3 = 0.f;
        float s4 = 0.f, s5 = 0.f, s6 = 0.f, s7 = 0.f;
#define RLF(m, acc) { int b_ = __builtin_amdgcn_readlane(pki, 2*(m)); \
        acc = FDOT(__builtin_bit_cast(half2_t, b_), e##m, acc); }
        RLF(0,  s0) RLF(1,  s1) RLF(2,  s2) RLF(3,  s3)
        RLF(4,  s4) RLF(5,  s5) RLF(6,  s6) RLF(7,  s7)
        RLF(8,  s0) RLF(9,  s1) RLF(10, s2) RLF(11, s3)
        RLF(12, s4) RLF(13, s5) RLF(14, s6) RLF(15, s7)
        RLF(16, s0) RLF(17, s1) RLF(18, s2) RLF(19, s3)
        RLF(20, s4) RLF(21, s5) RLF(22, s6) RLF(23, s7)
        RLF(24, s0)
#undef RLF
        float S = ((s0 + s1) + (s2 + s3)) + ((s4 + s5) + (s6 + s7));
        u = S * eexp;                                  // dead lanes: e==0 -> u stays 0
        int bb2 = __builtin_amdgcn_readlane(__float_as_int(u), 7);  // lane7 never dead
        kp = ((bb2 >> 23) & 255) - 127;
        rr = (127 - kp) << 23;
    };

    // --- depth-8 RAW prefetch (loads stay in flight; exp staged 1 step ahead) ---
    // qrD holds the RAW feat value; its first use (the exp) happens 7 steps
    // after the load issues, so the compiler's s_waitcnt keeps 7 loads in
    // flight instead of draining per step.
    float qr0, qr1, qr2, qr3, qr4, qr5, qr6, qr7;
    {
        int t0 = w ? (len - 2) : 1;
        int st = w ? -1 : 1;
#define LDR(qr, d) { int tl = t0 + st * (d); tl = (tl < 0) ? 0 : ((tl < TT) ? tl : TT - 1); \
                     qr = fb[(size_t)tl * NS + jj]; }
        LDR(qr0, 0) LDR(qr1, 1) LDR(qr2, 2) LDR(qr3, 3)
        LDR(qr4, 4) LDR(qr5, 5) LDR(qr6, 6) LDR(qr7, 7)
#undef LDR
    }
    float ecur = __expf(qr0);   // exp for the first step

    // position d: consume ecur (step k+d); reload qr_d (raw, step k+8+d);
    // stage ecur for step k+d+1 from qr_{(d+1)&7} (its load landed 7 steps ago).
#define PF_STEP(qr, qn, d) { \
        float e_ = ecur; \
        int kl = k + 8 + (d); \
        int tl = w ? (len - 2 - kl) : (1 + kl); \
        tl = (tl < 0) ? 0 : ((tl < TT) ? tl : TT - 1); \
        qr = fb[(size_t)tl * NS + jj]; \
        ecur = __expf(qn); \
        step(e_); }

    int k = 0;
    for (; k + 8 <= nst; k += 8) {
        PF_STEP(qr0, qr1, 0) PF_STEP(qr1, qr2, 1) PF_STEP(qr2, qr3, 2) PF_STEP(qr3, qr4, 3)
        PF_STEP(qr4, qr5, 4) PF_STEP(qr5, qr6, 5) PF_STEP(qr6, qr7, 6) PF_STEP(qr7, qr0, 7)
    }
#undef PF_STEP

    // tail (<8 steps): values for steps k..k+7 are already in qr0..qr7
    // (loaded during the last main-loop iteration); ecur = exp for step k.
#define TAIL_STEP(qn) if (k < nst) { float e_ = ecur; ecur = __expf(qn); step(e_); ++k; }
    TAIL_STEP(qr1) TAIL_STEP(qr2) TAIL_STEP(qr3) TAIL_STEP(qr4)
    TAIL_STEP(qr5) TAIL_STEP(qr6) TAIL_STEP(qr7)
#undef TAIL_STEP

    // --- bwd publishes ub*exp(-feat[tm]) (= exp(beta[tm]) scaled) and Kb ---
    if (w == 1) {
        sh_comb[lane] = u * __expf(-fb[(size_t)tm * NS + jj]);  // 0 for dead lanes
        if (lane == 0) sh_Kb = K;
    }

    // --- gold path score (exact, log-domain): both waves, stride-128 over t ---
    const int* tb = tags + (size_t)b * TT;
    float sc = 0.0f;
    for (int t2 = tid; t2 < len; t2 += 128) {
        int tg = tb[t2];
        sc += fb[(size_t)t2 * NS + tg];
        if (t2 >= 1) sc += trans[tb[t2 - 1] * NS + tg];
    }
    sc = wave_sum_f(sc);
    if (lane == 0) sh_sc[w] = sc;

    __syncthreads();

    if (w == 0) {
        // log_z = ln( sum_j uf_j * ub_j * exp(-feat[tm][j]) ) + (Kf+Kb)*ln2
        float wv = u * sh_comb[lane];         // dead lanes contribute 0
        float W = wave_sum_f(wv);
        float log_z = __logf(W) + (float)(K + sh_Kb) * 0.6931471805599453f;
        if (lane == 0) {
            float sct = sh_sc[0] + sh_sc[1]
                      + trans[tb[0]]                      // trans[ROOT][tag0]
                      + trans[tb[len - 1] * NS + 1];      // trans[tag_last][END]
            out[b] = log_z - sct;
        }
    }
}

extern "C" void kernel_launch(void* const* d_in, const int* in_sizes, int n_in,
                              void* d_out, int out_size, void* d_ws, size_t ws_size,
                              hipStream_t stream) {
    const float* feat  = (const float*)d_in[0];
    const float* trans = (const float*)d_in[1];
    const int*   tags  = (const int*)d_in[2];
    const int*   mask  = (const int*)d_in[3];
    float* out = (float*)d_out;
    crf_nll_kernel<<<dim3(BB), dim3(128), 0, stream>>>(feat, trans, tags, mask, out);
}

// Round 3
// 288.543 us; speedup vs baseline: 1.1162x; 1.1162x over previous
//
#include <hip/hip_runtime.h>
#include <math.h>

#define BB 512
#define TT 1024
#define NS 50
#define LCOLS 33   // padded LDS column stride (50 cols x 33 rows-slots)

typedef _Float16 half2_t __attribute__((ext_vector_type(2)));

static __device__ __forceinline__ half2_t pk_h2(float a, float b) {
    auto r = __builtin_amdgcn_cvt_pkrtz(a, b);   // packs (a -> lo, b -> hi)
    return __builtin_bit_cast(half2_t, r);
}
static __device__ __forceinline__ float wave_sum_f(float v) {
    #pragma unroll
    for (int k = 32; k >= 1; k >>= 1) v += __shfl_xor(v, k, 64);
    return v;
}
static __device__ __forceinline__ int wave_sum_i(int v) {
    #pragma unroll
    for (int k = 32; k >= 1; k >>= 1) v += __shfl_xor(v, k, 64);
    return v;
}
#define FDOT(a, b, c) __builtin_amdgcn_fdot2((a), (b), (c), false)

__global__ __launch_bounds__(128, 1) void crf_nll_kernel(
    const float* __restrict__ feat,    // (B, T, N)
    const float* __restrict__ trans,   // (N, N)
    const int*   __restrict__ tags,    // (B, T)
    const int*   __restrict__ mask,    // (B, T)
    float* __restrict__ out)           // (B,)
{
    const int b    = blockIdx.x;
    const int tid  = threadIdx.x;
    const int w    = tid >> 6;        // wave 0 = forward, wave 1 = backward (zeta)
    const int lane = tid & 63;
    const int jj   = (lane < NS) ? lane : 0;

    __shared__ float sh_comb[64];
    __shared__ float sh_sc[2];
    __shared__ int   sh_Kb;
    // pre-exp'd feat chunks: [wave][double-buf][col*33 + rowslot]
    __shared__ float lds[2][2][NS * LCOLS];

    // --- E fragments as 25 named packed-f16 regs (register-resident).
    // fwd: e_m = (E[2m][j], E[2m+1][j]);  bwd: e_m = (E[j][2m], E[j][2m+1])
    // exp(-10000) == 0 exactly -> forbidden transitions vanish.
#define INIT_E(m) half2_t e##m; { \
        int r0 = w ? (jj * NS + 2*(m)) : ((2*(m)) * NS + jj); \
        int r1 = r0 + (w ? 1 : NS); \
        float x0 = __expf(trans[r0]); \
        float x1 = __expf(trans[r1]); \
        if (lane >= NS) { x0 = 0.f; x1 = 0.f; } \
        e##m = pk_h2(x0, x1); }
    INIT_E(0)  INIT_E(1)  INIT_E(2)  INIT_E(3)  INIT_E(4)
    INIT_E(5)  INIT_E(6)  INIT_E(7)  INIT_E(8)  INIT_E(9)
    INIT_E(10) INIT_E(11) INIT_E(12) INIT_E(13) INIT_E(14)
    INIT_E(15) INIT_E(16) INIT_E(17) INIT_E(18) INIT_E(19)
    INIT_E(20) INIT_E(21) INIT_E(22) INIT_E(23) INIT_E(24)
#undef INIT_E

    // --- sequence length (mask is a prefix of ones); uniform ---
    int cnt = 0;
    for (int t = lane; t < TT; t += 64) cnt += mask[b * TT + t];
    const int len = wave_sum_i(cnt);
    const int tm  = (len - 1) >> 1;          // cut point
    const int nst = w ? (len - 1 - tm) : tm; // steps this wave runs

    const float* fb = feat + (size_t)b * TT * NS;

    // --- prob-domain init: fwd u=exp(alpha0); bwd u=exp(zeta_{len-1}), zeta=beta+feat
    float u;
    if (w == 0) u = (lane < NS) ? __expf(trans[jj] + fb[jj]) : 0.f;
    else        u = (lane < NS) ? __expf(trans[jj * NS + 1] + fb[(size_t)(len - 1) * NS + jj]) : 0.f;
    int K = 0, kp, rr;
    { int bb2 = __builtin_amdgcn_readlane(__float_as_int(u), 7);
      kp = ((bb2 >> 23) & 255) - 127; rr = (127 - kp) << 23; }

    // --- one step (identical math to the 157us version). eexp comes from LDS. ---
    auto step = [&](float eexp) {
        K += kp;
        float p = u * __int_as_float(rr);             // lane7 in [1,2); others e^±spread
        int pn_ = __builtin_amdgcn_update_dpp(
            __float_as_int(p), __float_as_int(p), 0xB1, 0xF, 0xF, true); // lane^1
        float pnf = __int_as_float(pn_);
        half2_t pk = pk_h2(p, pnf);                   // even lane: (u[2m], u[2m+1])
        int pki = __builtin_bit_cast(int, pk);
        float s0 = 0.f, s1 = 0.f, s2 = 0.f, s3 = 0.f;
        float s4 = 0.f, s5 = 0.f, s6 = 0.f, s7 = 0.f;
#define RLF(m, acc) { int b_ = __builtin_amdgcn_readlane(pki, 2*(m)); \
        acc = FDOT(__builtin_bit_cast(half2_t, b_), e##m, acc); }
        RLF(0,  s0) RLF(1,  s1) RLF(2,  s2) RLF(3,  s3)
        RLF(4,  s4) RLF(5,  s5) RLF(6,  s6) RLF(7,  s7)
        RLF(8,  s0) RLF(9,  s1) RLF(10, s2) RLF(11, s3)
        RLF(12, s4) RLF(13, s5) RLF(14, s6) RLF(15, s7)
        RLF(16, s0) RLF(17, s1) RLF(18, s2) RLF(19, s3)
        RLF(20, s4) RLF(21, s5) RLF(22, s6) RLF(23, s7)
        RLF(24, s0)
#undef RLF
        float S = ((s0 + s1) + (s2 + s3)) + ((s4 + s5) + (s6 + s7));
        u = S * eexp;                                  // dead lanes: e==0 -> u stays 0
        int bb2 = __builtin_amdgcn_readlane(__float_as_int(u), 7);  // lane7 never dead
        kp = ((bb2 >> 23) & 255) - 127;
        rr = (127 - kp) << 23;
    };

    // =====================================================================
    // Bulk LDS staging of pre-exp'd feat rows, 32 rows (one chunk) at a time.
    // Inner loop has ZERO global loads and ZERO exp — only ds_read2-able
    // LDS reads, prefetched one 8-step group ahead.
    //
    // fwd step k uses row t = 1+k        -> LDS slot (k&31)
    // bwd step k uses row t = len-2-k    -> LDS slot (k&31) (flipped at write)
    // =====================================================================
    auto chunk_base = [&](int cs) -> int {
        int bs = w ? (len - 33 - 32 * cs) : (1 + 32 * cs);
        return bs < 0 ? 0 : bs;
    };

    float2 g0, g1, g2, g3, g4, g5, g6, g7, g8, g9, g10, g11, g12;
    g12.x = 0.f; g12.y = 0.f;
    auto issue_loads = [&](int cs) {
        int base = chunk_base(cs);
        const float2* gp = (const float2*)(fb + (size_t)base * NS);
        g0  = gp[0*64  + lane];  g1  = gp[1*64  + lane];
        g2  = gp[2*64  + lane];  g3  = gp[3*64  + lane];
        g4  = gp[4*64  + lane];  g5  = gp[5*64  + lane];
        g6  = gp[6*64  + lane];  g7  = gp[7*64  + lane];
        g8  = gp[8*64  + lane];  g9  = gp[9*64  + lane];
        g10 = gp[10*64 + lane];  g11 = gp[11*64 + lane];
        if (lane < 32) g12 = gp[12*64 + lane];
    };
    auto exp_write = [&](int cs, float* L) {
        int base = chunk_base(cs);
        int LD2  = len - 2 - 32 * cs;     // bwd: slot = LD2 - global_row
#define WR(gi, i) { \
        int d   = (i) * 128 + lane * 2; \
        int r   = d / 50; \
        int col = d - r * 50; \
        int sr  = w ? (LD2 - (base + r)) : r; \
        bool ok = (((i) < 12) || (lane < 32)) && (sr >= 0) && (sr < 32); \
        if (ok) { L[col * LCOLS + sr]       = __expf(gi.x); \
                  L[(col + 1) * LCOLS + sr] = __expf(gi.y); } }
        WR(g0,0)  WR(g1,1)  WR(g2,2)  WR(g3,3)  WR(g4,4)  WR(g5,5)
        WR(g6,6)  WR(g7,7)  WR(g8,8)  WR(g9,9)  WR(g10,10) WR(g11,11)
        WR(g12,12)
#undef WR
    };

    float c0, c1, c2, c3, c4, c5, c6, c7;   // eexp for current 8-step group
    auto prime = [&](const float* L) {
        const float* Lp = L + jj * LCOLS;
        c0 = Lp[0]; c1 = Lp[1]; c2 = Lp[2]; c3 = Lp[3];
        c4 = Lp[4]; c5 = Lp[5]; c6 = Lp[6]; c7 = Lp[7];
    };

    const int nfull = nst >> 5;
    const int tail  = nst & 31;

    // prologue: stage chunk 0, start loads for chunk 1, prime first group
    issue_loads(0);
    exp_write(0, &lds[w][0][0]);
    issue_loads(1);
    __asm__ volatile("s_waitcnt lgkmcnt(0)" ::: "memory");
    __builtin_amdgcn_sched_barrier(0);
    prime(&lds[w][0][0]);

    int bufc = 0;
    for (int c = 0; c < nfull; ++c) {
        const float* L  = &lds[w][bufc][0] + jj * LCOLS;
        #pragma unroll 1
        for (int it = 0; it < 4; ++it) {
            int nidx = ((it + 1) * 8) & 31;              // next group (wraps on last)
            float n0 = L[nidx + 0], n1 = L[nidx + 1], n2 = L[nidx + 2], n3 = L[nidx + 3];
            float n4 = L[nidx + 4], n5 = L[nidx + 5], n6 = L[nidx + 6], n7 = L[nidx + 7];
            step(c0); step(c1); step(c2); step(c3);
            step(c4); step(c5); step(c6); step(c7);
            c0 = n0; c1 = n1; c2 = n2; c3 = n3;
            c4 = n4; c5 = n5; c6 = n6; c7 = n7;
        }
        // chunk boundary: loads for chunk c+1 finished ~32 steps ago
        float* Lnxt = &lds[w][bufc ^ 1][0];
        exp_write(c + 1, Lnxt);          // compiler inserts the (free) vmcnt wait
        issue_loads(c + 2);              // in flight during next chunk
        __asm__ volatile("s_waitcnt lgkmcnt(0)" ::: "memory");
        __builtin_amdgcn_sched_barrier(0);
        prime(Lnxt);
        bufc ^= 1;
    }

    if (tail) {
        const float* L = &lds[w][bufc][0] + jj * LCOLS;
        int rem = tail;
        #pragma unroll 1
        for (int it = 0; it < 4 && rem > 0; ++it) {
            int nidx = ((it + 1) * 8) & 31;
            float n0 = L[nidx + 0], n1 = L[nidx + 1], n2 = L[nidx + 2], n3 = L[nidx + 3];
            float n4 = L[nidx + 4], n5 = L[nidx + 5], n6 = L[nidx + 6], n7 = L[nidx + 7];
            if (rem > 0) { step(c0); --rem; }
            if (rem > 0) { step(c1); --rem; }
            if (rem > 0) { step(c2); --rem; }
            if (rem > 0) { step(c3); --rem; }
            if (rem > 0) { step(c4); --rem; }
            if (rem > 0) { step(c5); --rem; }
            if (rem > 0) { step(c6); --rem; }
            if (rem > 0) { step(c7); --rem; }
            c0 = n0; c1 = n1; c2 = n2; c3 = n3;
            c4 = n4; c5 = n5; c6 = n6; c7 = n7;
        }
    }

    // --- bwd publishes ub*exp(-feat[tm]) (= exp(beta[tm]) scaled) and Kb ---
    if (w == 1) {
        sh_comb[lane] = u * __expf(-fb[(size_t)tm * NS + jj]);  // 0 for dead lanes
        if (lane == 0) sh_Kb = K;
    }

    // --- gold path score (exact, log-domain): both waves, stride-128 over t ---
    const int* tb = tags + (size_t)b * TT;
    float sc = 0.0f;
    for (int t2 = tid; t2 < len; t2 += 128) {
        int tg = tb[t2];
        sc += fb[(size_t)t2 * NS + tg];
        if (t2 >= 1) sc += trans[tb[t2 - 1] * NS + tg];
    }
    sc = wave_sum_f(sc);
    if (lane == 0) sh_sc[w] = sc;

    __syncthreads();

    if (w == 0) {
        // log_z = ln( sum_j uf_j * ub_j * exp(-feat[tm][j]) ) + (Kf+Kb)*ln2
        float wv = u * sh_comb[lane];         // dead lanes contribute 0
        float W = wave_sum_f(wv);
        float log_z = __logf(W) + (float)(K + sh_Kb) * 0.6931471805599453f;
        if (lane == 0) {
            float sct = sh_sc[0] + sh_sc[1]
                      + trans[tb[0]]                      // trans[ROOT][tag0]
                      + trans[tb[len - 1] * NS + 1];      // trans[tag_last][END]
            out[b] = log_z - sct;
        }
    }
}

extern "C" void kernel_launch(void* const* d_in, const int* in_sizes, int n_in,
                              void* d_out, int out_size, void* d_ws, size_t ws_size,
                              hipStream_t stream) {
    const float* feat  = (const float*)d_in[0];
    const float* trans = (const float*)d_in[1];
    const int*   tags  = (const int*)d_in[2];
    const int*   mask  = (const int*)d_in[3];
    float* out = (float*)d_out;
    crf_nll_kernel<<<dim3(BB), dim3(128), 0, stream>>>(feat, trans, tags, mask, out);
}

// Round 4
// 271.063 us; speedup vs baseline: 1.1882x; 1.0645x over previous
//
#include <hip/hip_runtime.h>
#include <math.h>

#define BB 512
#define TT 1024
#define NS 50
#define LCOLS 33   // padded LDS column stride (50 cols x 33 rows-slots)

typedef _Float16 half2_t __attribute__((ext_vector_type(2)));

static __device__ __forceinline__ half2_t pk_h2(float a, float b) {
    auto r = __builtin_amdgcn_cvt_pkrtz(a, b);   // packs (a -> lo, b -> hi)
    return __builtin_bit_cast(half2_t, r);
}
static __device__ __forceinline__ float wave_sum_f(float v) {
    #pragma unroll
    for (int k = 32; k >= 1; k >>= 1) v += __shfl_xor(v, k, 64);
    return v;
}
static __device__ __forceinline__ int wave_sum_i(int v) {
    #pragma unroll
    for (int k = 32; k >= 1; k >>= 1) v += __shfl_xor(v, k, 64);
    return v;
}
#define FDOT(a, b, c) __builtin_amdgcn_fdot2((a), (b), (c), false)

__global__ __launch_bounds__(128, 1) void crf_nll_kernel(
    const float* __restrict__ feat,    // (B, T, N)
    const float* __restrict__ trans,   // (N, N)
    const int*   __restrict__ tags,    // (B, T)
    const int*   __restrict__ mask,    // (B, T)
    float* __restrict__ out)           // (B,)
{
    const int b    = blockIdx.x;
    const int tid  = threadIdx.x;
    const int w    = tid >> 6;        // wave 0 = forward, wave 1 = backward (zeta)
    const int lane = tid & 63;
    const int jj   = (lane < NS) ? lane : 0;

    __shared__ float sh_comb[64];
    __shared__ float sh_sc[2];
    __shared__ int   sh_Kb;
    // pre-exp'd feat chunks: [wave][double-buf][col*33 + rowslot]
    __shared__ float lds[2][2][NS * LCOLS];

    // --- E fragments as 25 named packed-f16 regs (register-resident).
    // fwd: e_m = (E[2m][j], E[2m+1][j]);  bwd: e_m = (E[j][2m], E[j][2m+1])
    // exp(-10000) == 0 exactly -> forbidden transitions vanish.
#define INIT_E(m) half2_t e##m; { \
        int r0 = w ? (jj * NS + 2*(m)) : ((2*(m)) * NS + jj); \
        int r1 = r0 + (w ? 1 : NS); \
        float x0 = __expf(trans[r0]); \
        float x1 = __expf(trans[r1]); \
        if (lane >= NS) { x0 = 0.f; x1 = 0.f; } \
        e##m = pk_h2(x0, x1); }
    INIT_E(0)  INIT_E(1)  INIT_E(2)  INIT_E(3)  INIT_E(4)
    INIT_E(5)  INIT_E(6)  INIT_E(7)  INIT_E(8)  INIT_E(9)
    INIT_E(10) INIT_E(11) INIT_E(12) INIT_E(13) INIT_E(14)
    INIT_E(15) INIT_E(16) INIT_E(17) INIT_E(18) INIT_E(19)
    INIT_E(20) INIT_E(21) INIT_E(22) INIT_E(23) INIT_E(24)
#undef INIT_E

    // --- sequence length (mask is a prefix of ones); uniform ---
    int cnt = 0;
    for (int t = lane; t < TT; t += 64) cnt += mask[b * TT + t];
    const int len = wave_sum_i(cnt);
    const int tm  = (len - 1) >> 1;          // cut point
    const int nst = w ? (len - 1 - tm) : tm; // steps this wave runs

    const float* fb = feat + (size_t)b * TT * NS;

    // --- prob-domain init: fwd u=exp(alpha0); bwd u=exp(zeta_{len-1}), zeta=beta+feat
    float u;
    if (w == 0) u = (lane < NS) ? __expf(trans[jj] + fb[jj]) : 0.f;
    else        u = (lane < NS) ? __expf(trans[jj * NS + 1] + fb[(size_t)(len - 1) * NS + jj]) : 0.f;
    int K = 0, kp, rlp;
    { int bb2 = __builtin_amdgcn_readlane(__float_as_int(u), 7);
      kp = ((bb2 >> 23) & 255) - 127; }
    rlp = 0x3F800000;   // exponent 0: first step's kp stays = exponent(u0[7])

    // --- one step. eexp comes from LDS (pre-exp'd, lane-private).
    // Rescale pipeline: p[7] in [1,2) always => exponent(p[7]) = exponent(u[7]) - kp
    // exactly, so kp_next = kp + eps(p) is BIT-IDENTICAL to readlane(u_next,7)'s
    // exponent computed the old way -- but the readlane now has a whole step of slack.
    // Broadcast: 25 readlanes batched FIRST, sched_barrier, then 25 fdots --
    // every fdot reads an SGPR written >=25 instructions earlier (no hazard pairs).
    auto step = [&](float eexp) {
        kp += ((rlp >> 23) & 255) - 127;      // SALU, operand ready since last step
        K  += kp;
        int rr = (127 - kp) << 23;
        float p = u * __int_as_float(rr);     // lane7 in [1,2); others e^±spread
        rlp = __builtin_amdgcn_readlane(__float_as_int(p), 7);  // for NEXT step
        int pn_ = __builtin_amdgcn_update_dpp(
            __float_as_int(p), __float_as_int(p), 0xB1, 0xF, 0xF, true); // lane^1
        float pnf = __int_as_float(pn_);
        half2_t pk = pk_h2(p, pnf);           // even lane: (u[2m], u[2m+1])
        int pki = __builtin_bit_cast(int, pk);
        // ---- phase 1: batch all broadcasts (independent, issue back-to-back)
        int r0_  = __builtin_amdgcn_readlane(pki, 0);
        int r1_  = __builtin_amdgcn_readlane(pki, 2);
        int r2_  = __builtin_amdgcn_readlane(pki, 4);
        int r3_  = __builtin_amdgcn_readlane(pki, 6);
        int r4_  = __builtin_amdgcn_readlane(pki, 8);
        int r5_  = __builtin_amdgcn_readlane(pki, 10);
        int r6_  = __builtin_amdgcn_readlane(pki, 12);
        int r7_  = __builtin_amdgcn_readlane(pki, 14);
        int r8_  = __builtin_amdgcn_readlane(pki, 16);
        int r9_  = __builtin_amdgcn_readlane(pki, 18);
        int r10_ = __builtin_amdgcn_readlane(pki, 20);
        int r11_ = __builtin_amdgcn_readlane(pki, 22);
        int r12_ = __builtin_amdgcn_readlane(pki, 24);
        int r13_ = __builtin_amdgcn_readlane(pki, 26);
        int r14_ = __builtin_amdgcn_readlane(pki, 28);
        int r15_ = __builtin_amdgcn_readlane(pki, 30);
        int r16_ = __builtin_amdgcn_readlane(pki, 32);
        int r17_ = __builtin_amdgcn_readlane(pki, 34);
        int r18_ = __builtin_amdgcn_readlane(pki, 36);
        int r19_ = __builtin_amdgcn_readlane(pki, 38);
        int r20_ = __builtin_amdgcn_readlane(pki, 40);
        int r21_ = __builtin_amdgcn_readlane(pki, 42);
        int r22_ = __builtin_amdgcn_readlane(pki, 44);
        int r23_ = __builtin_amdgcn_readlane(pki, 46);
        int r24_ = __builtin_amdgcn_readlane(pki, 48);
        __builtin_amdgcn_sched_barrier(0);
        // ---- phase 2: the 25 dots (8 independent accumulator chains)
        float s0 = 0.f, s1 = 0.f, s2 = 0.f, s3 = 0.f;
        float s4 = 0.f, s5 = 0.f, s6 = 0.f, s7 = 0.f;
#define FD(r, em, acc) acc = FDOT(__builtin_bit_cast(half2_t, r), em, acc);
        FD(r0_,  e0,  s0) FD(r1_,  e1,  s1) FD(r2_,  e2,  s2) FD(r3_,  e3,  s3)
        FD(r4_,  e4,  s4) FD(r5_,  e5,  s5) FD(r6_,  e6,  s6) FD(r7_,  e7,  s7)
        FD(r8_,  e8,  s0) FD(r9_,  e9,  s1) FD(r10_, e10, s2) FD(r11_, e11, s3)
        FD(r12_, e12, s4) FD(r13_, e13, s5) FD(r14_, e14, s6) FD(r15_, e15, s7)
        FD(r16_, e16, s0) FD(r17_, e17, s1) FD(r18_, e18, s2) FD(r19_, e19, s3)
        FD(r20_, e20, s4) FD(r21_, e21, s5) FD(r22_, e22, s6) FD(r23_, e23, s7)
        FD(r24_, e24, s0)
#undef FD
        float S = ((s0 + s1) + (s2 + s3)) + ((s4 + s5) + (s6 + s7));
        u = S * eexp;                          // dead lanes: e==0 -> u stays 0
    };

    // =====================================================================
    // Bulk LDS staging of pre-exp'd feat rows, 32 rows (one chunk) at a time.
    // Inner loop has ZERO global loads and ZERO exp.
    // fwd step k uses row t = 1+k        -> LDS slot (k&31)
    // bwd step k uses row t = len-2-k    -> LDS slot (k&31) (flipped at write)
    // =====================================================================
    auto chunk_base = [&](int cs) -> int {
        int bs = w ? (len - 33 - 32 * cs) : (1 + 32 * cs);
        return bs < 0 ? 0 : bs;
    };

    float2 g0, g1, g2, g3, g4, g5, g6, g7, g8, g9, g10, g11, g12;
    g12.x = 0.f; g12.y = 0.f;
    auto issue_loads = [&](int cs) {
        int base = chunk_base(cs);
        const float2* gp = (const float2*)(fb + (size_t)base * NS);
        g0  = gp[0*64  + lane];  g1  = gp[1*64  + lane];
        g2  = gp[2*64  + lane];  g3  = gp[3*64  + lane];
        g4  = gp[4*64  + lane];  g5  = gp[5*64  + lane];
        g6  = gp[6*64  + lane];  g7  = gp[7*64  + lane];
        g8  = gp[8*64  + lane];  g9  = gp[9*64  + lane];
        g10 = gp[10*64 + lane];  g11 = gp[11*64 + lane];
        if (lane < 32) g12 = gp[12*64 + lane];
    };
    auto exp_write = [&](int cs, float* L) {
        int base = chunk_base(cs);
        int LD2  = len - 2 - 32 * cs;     // bwd: slot = LD2 - global_row
#define WR(gi, i) { \
        int d   = (i) * 128 + lane * 2; \
        int r   = d / 50; \
        int col = d - r * 50; \
        int sr  = w ? (LD2 - (base + r)) : r; \
        bool ok = (((i) < 12) || (lane < 32)) && (sr >= 0) && (sr < 32); \
        if (ok) { L[col * LCOLS + sr]       = __expf(gi.x); \
                  L[(col + 1) * LCOLS + sr] = __expf(gi.y); } }
        WR(g0,0)  WR(g1,1)  WR(g2,2)  WR(g3,3)  WR(g4,4)  WR(g5,5)
        WR(g6,6)  WR(g7,7)  WR(g8,8)  WR(g9,9)  WR(g10,10) WR(g11,11)
        WR(g12,12)
#undef WR
    };

    float c0, c1, c2, c3, c4, c5, c6, c7;   // eexp for current 8-step group
    auto prime = [&](const float* L) {
        const float* Lp = L + jj * LCOLS;
        c0 = Lp[0]; c1 = Lp[1]; c2 = Lp[2]; c3 = Lp[3];
        c4 = Lp[4]; c5 = Lp[5]; c6 = Lp[6]; c7 = Lp[7];
    };

    const int nfull = nst >> 5;
    const int tail  = nst & 31;

    // prologue: stage chunk 0, start loads for chunk 1, prime first group
    issue_loads(0);
    exp_write(0, &lds[w][0][0]);
    issue_loads(1);
    __asm__ volatile("s_waitcnt lgkmcnt(0)" ::: "memory");
    __builtin_amdgcn_sched_barrier(0);
    prime(&lds[w][0][0]);

    int bufc = 0;
    for (int c = 0; c < nfull; ++c) {
        const float* L  = &lds[w][bufc][0] + jj * LCOLS;
        #pragma unroll 1
        for (int it = 0; it < 4; ++it) {
            int nidx = ((it + 1) * 8) & 31;              // next group (wraps on last)
            float n0 = L[nidx + 0], n1 = L[nidx + 1], n2 = L[nidx + 2], n3 = L[nidx + 3];
            float n4 = L[nidx + 4], n5 = L[nidx + 5], n6 = L[nidx + 6], n7 = L[nidx + 7];
            step(c0); step(c1); step(c2); step(c3);
            step(c4); step(c5); step(c6); step(c7);
            c0 = n0; c1 = n1; c2 = n2; c3 = n3;
            c4 = n4; c5 = n5; c6 = n6; c7 = n7;
        }
        // chunk boundary: loads for chunk c+1 finished ~32 steps ago
        float* Lnxt = &lds[w][bufc ^ 1][0];
        exp_write(c + 1, Lnxt);          // compiler inserts the (free) vmcnt wait
        issue_loads(c + 2);              // in flight during next chunk
        __asm__ volatile("s_waitcnt lgkmcnt(0)" ::: "memory");
        __builtin_amdgcn_sched_barrier(0);
        prime(Lnxt);
        bufc ^= 1;
    }

    if (tail) {
        const float* L = &lds[w][bufc][0] + jj * LCOLS;
        int rem = tail;
        #pragma unroll 1
        for (int it = 0; it < 4 && rem > 0; ++it) {
            int nidx = ((it + 1) * 8) & 31;
            float n0 = L[nidx + 0], n1 = L[nidx + 1], n2 = L[nidx + 2], n3 = L[nidx + 3];
            float n4 = L[nidx + 4], n5 = L[nidx + 5], n6 = L[nidx + 6], n7 = L[nidx + 7];
            if (rem > 0) { step(c0); --rem; }
            if (rem > 0) { step(c1); --rem; }
            if (rem > 0) { step(c2); --rem; }
            if (rem > 0) { step(c3); --rem; }
            if (rem > 0) { step(c4); --rem; }
            if (rem > 0) { step(c5); --rem; }
            if (rem > 0) { step(c6); --rem; }
            if (rem > 0) { step(c7); --rem; }
            c0 = n0; c1 = n1; c2 = n2; c3 = n3;
            c4 = n4; c5 = n5; c6 = n6; c7 = n7;
        }
    }

    // --- bwd publishes ub*exp(-feat[tm]) (= exp(beta[tm]) scaled) and Kb ---
    if (w == 1) {
        sh_comb[lane] = u * __expf(-fb[(size_t)tm * NS + jj]);  // 0 for dead lanes
        if (lane == 0) sh_Kb = K;
    }

    // --- gold path score (exact, log-domain): both waves, stride-128 over t ---
    const int* tb = tags + (size_t)b * TT;
    float sc = 0.0f;
    for (int t2 = tid; t2 < len; t2 += 128) {
        int tg = tb[t2];
        sc += fb[(size_t)t2 * NS + tg];
        if (t2 >= 1) sc += trans[tb[t2 - 1] * NS + tg];
    }
    sc = wave_sum_f(sc);
    if (lane == 0) sh_sc[w] = sc;

    __syncthreads();

    if (w == 0) {
        // log_z = ln( sum_j uf_j * ub_j * exp(-feat[tm][j]) ) + (Kf+Kb)*ln2
        float wv = u * sh_comb[lane];         // dead lanes contribute 0
        float W = wave_sum_f(wv);
        float log_z = __logf(W) + (float)(K + sh_Kb) * 0.6931471805599453f;
        if (lane == 0) {
            float sct = sh_sc[0] + sh_sc[1]
                      + trans[tb[0]]                      // trans[ROOT][tag0]
                      + trans[tb[len - 1] * NS + 1];      // trans[tag_last][END]
            out[b] = log_z - sct;
        }
    }
}

extern "C" void kernel_launch(void* const* d_in, const int* in_sizes, int n_in,
                              void* d_out, int out_size, void* d_ws, size_t ws_size,
                              hipStream_t stream) {
    const float* feat  = (const float*)d_in[0];
    const float* trans = (const float*)d_in[1];
    const int*   tags  = (const int*)d_in[2];
    const int*   mask  = (const int*)d_in[3];
    float* out = (float*)d_out;
    crf_nll_kernel<<<dim3(BB), dim3(128), 0, stream>>>(feat, trans, tags, mask, out);
}